// Round 7
// baseline (87.273 us; speedup 1.0000x reference)
//
#include <hip/hip_runtime.h>

namespace {

constexpr int Hh = 512, Ww = 512, OH = 1024, OW = 1024;
constexpr int NB_YP = 128;            // blocks of 2 y-blocks (4 input rows)
constexpr int NBC   = 48;             // 16 batches * 3 out channels
constexpr int NWG   = NB_YP * NBC;    // 6144, % 8 == 0

typedef float f32x4 __attribute__((ext_vector_type(4)));

// Haar butterfly, 2 input rows per thread.
// Thread: input rows (y0, y0+1), 4 cols -> 8x4 output strip, 4 bands.
// Loads 4 rows x 4 bands = 16 dwordx4 (vs 24 for 2 single-row threads).
__global__ __launch_bounds__(256) void ihaar(
    const float* __restrict__ x,
    const float* __restrict__ f0,
    const float* __restrict__ f1,
    const float* __restrict__ f2,
    const float* __restrict__ f3,
    float* __restrict__ out)
{
  // XCD-chunked bijective swizzle (NWG % 8 == 0)
  const int bid = blockIdx.x;
  const int wg  = (bid & 7) * (NWG / 8) + (bid >> 3);
  const int bc  = wg / NB_YP;
  const int ybp = wg - bc * NB_YP;
  const int b = bc / 3;
  const int c = bc - 3 * b;

  const int t    = threadIdx.x;
  const int lane = t & 63;
  const int wv   = t >> 6;
  const int half = wv & 1;              // col half (0: 0..255, 1: 256..511)
  const int sub  = wv >> 1;             // which y-block within the pair
  const int y0   = 4 * ybp + 2 * sub;   // even input row 0..510
  const int y1   = y0 + 1;
  const int x0   = half * 256 + lane * 4;

  const int rm = (y0 > 0) ? y0 - 1 : 0;
  const int rt = (y1 < Hh - 1) ? y1 + 1 : Hh - 1;

  const bool needL = (lane == 0)  && (half == 1);   // needs col 255
  const bool needR = (lane == 63) && (half == 0);   // needs col 256
  const bool seam  = needL || needR;
  const bool le = (x0 == 0), re = (x0 == Ww - 4);
  const int sc = needL ? (x0 - 1) : (x0 + 4);

  const size_t HW = (size_t)Hh * Ww;
  const float* Xa = x + (size_t)(b * 12 + c) * HW;
  const float* Xb = Xa + 3 * HW;
  const float* Xc = Xa + 6 * HW;
  const float* Xd = Xa + 9 * HW;
  const size_t om = (size_t)rm * Ww + x0;
  const size_t orr = (size_t)y0 * Ww + x0;
  const size_t os = (size_t)y1 * Ww + x0;
  const size_t ot = (size_t)rt * Ww + x0;

  // ---- all 16 vector loads ----
  const f32x4 qAm = *(const f32x4*)(Xa + om), qAr = *(const f32x4*)(Xa + orr);
  const f32x4 qAs = *(const f32x4*)(Xa + os), qAt = *(const f32x4*)(Xa + ot);
  const f32x4 qBm = *(const f32x4*)(Xb + om), qBr = *(const f32x4*)(Xb + orr);
  const f32x4 qBs = *(const f32x4*)(Xb + os), qBt = *(const f32x4*)(Xb + ot);
  const f32x4 qCm = *(const f32x4*)(Xc + om), qCr = *(const f32x4*)(Xc + orr);
  const f32x4 qCs = *(const f32x4*)(Xc + os), qCt = *(const f32x4*)(Xc + ot);
  const f32x4 qDm = *(const f32x4*)(Xd + om), qDr = *(const f32x4*)(Xd + orr);
  const f32x4 qDs = *(const f32x4*)(Xd + os), qDt = *(const f32x4*)(Xd + ot);

  float sAm=0.f,sAr=0.f,sAs=0.f,sAt=0.f, sBm=0.f,sBr=0.f,sBs=0.f,sBt=0.f;
  float sCm=0.f,sCr=0.f,sCs=0.f,sCt=0.f, sDm=0.f,sDr=0.f,sDs=0.f,sDt=0.f;
  if (seam) {
    const size_t tm = (size_t)rm * Ww + sc, tr = (size_t)y0 * Ww + sc;
    const size_t ts = (size_t)y1 * Ww + sc, tt = (size_t)rt * Ww + sc;
    sAm = Xa[tm]; sAr = Xa[tr]; sAs = Xa[ts]; sAt = Xa[tt];
    sBm = Xb[tm]; sBr = Xb[tr]; sBs = Xb[ts]; sBt = Xb[tt];
    sCm = Xc[tm]; sCr = Xc[tr]; sCs = Xc[ts]; sCt = Xc[tt];
    sDm = Xd[tm]; sDr = Xd[tr]; sDs = Xd[ts]; sDt = Xd[tt];
  }

  const float4 F[4] = { *(const float4*)f0, *(const float4*)f1,
                        *(const float4*)f2, *(const float4*)f3 };

  // group accumulators: (P, Q) x 4 parities x 4 cols
  float PE0a=0.f,PE0b=0.f,PE0c=0.f,PE0d=0.f, PO0a=0.f,PO0b=0.f,PO0c=0.f,PO0d=0.f;
  float PE1a=0.f,PE1b=0.f,PE1c=0.f,PE1d=0.f, PO1a=0.f,PO1b=0.f,PO1c=0.f,PO1d=0.f;
  float QE0a=0.f,QE0b=0.f,QE0c=0.f,QE0d=0.f, QO0a=0.f,QO0b=0.f,QO0c=0.f,QO0d=0.f;
  float QE1a=0.f,QE1b=0.f,QE1c=0.f,QE1d=0.f, QO1a=0.f,QO1b=0.f,QO1c=0.f,QO1d=0.f;
  float SPE0=0.f,SPO0=0.f,SPE1=0.f,SPO1=0.f;
  float SQE0=0.f,SQO0=0.f,SQE1=0.f,SQO1=0.f;

  // Vertical taps per band over rows (m,r,s,t):
  //  E0 (out 2y0):   pa(y0) over (m,r)   — y0==0 edge: (0, u1)
  //  O0 (out 2y0+1): pb(y0) over (m,r,s) — y0==0 edge
  //  E1 (out 2y0+2): pa(y1) over (r,s)   — always interior (y1>=1)
  //  O1 (out 2y0+3): pb(y1) over (r,s,t) — y1==511 edge
#define BANDV(g, qm,qr,qs,qt, sm,sr,ss,st, GE0,GO0,GE1,GO1, SE0,SO0,SE1,SO1) { \
    const float uu0 = F[g].x, uu1 = F[g].z; \
    const float pa0 = 0.75f*uu0 + 0.25f*uu1; \
    const float pa1 = 0.25f*uu0 + 0.75f*uu1; \
    const float eA0 = (y0 > 0) ? pa0 : 0.f; \
    const float eA1 = (y0 > 0) ? pa1 : uu1; \
    const float o00 = (y0 > 0) ? 0.25f*uu0 : 0.f; \
    const float o01 = (y0 > 0) ? 0.75f*(uu0+uu1) : (uu0 + 0.75f*uu1); \
    const float o02 = 0.25f*uu1; \
    const float o10 = 0.25f*uu0; \
    const float o11 = (y1 < Hh-1) ? 0.75f*(uu0+uu1) : (0.75f*uu0 + uu1); \
    const float o12 = (y1 < Hh-1) ? 0.25f*uu1 : 0.f; \
    GE0##a += eA0*qm.x + eA1*qr.x;  GE0##b += eA0*qm.y + eA1*qr.y; \
    GE0##c += eA0*qm.z + eA1*qr.z;  GE0##d += eA0*qm.w + eA1*qr.w; \
    GO0##a += o00*qm.x + o01*qr.x + o02*qs.x; \
    GO0##b += o00*qm.y + o01*qr.y + o02*qs.y; \
    GO0##c += o00*qm.z + o01*qr.z + o02*qs.z; \
    GO0##d += o00*qm.w + o01*qr.w + o02*qs.w; \
    GE1##a += pa0*qr.x + pa1*qs.x;  GE1##b += pa0*qr.y + pa1*qs.y; \
    GE1##c += pa0*qr.z + pa1*qs.z;  GE1##d += pa0*qr.w + pa1*qs.w; \
    GO1##a += o10*qr.x + o11*qs.x + o12*qt.x; \
    GO1##b += o10*qr.y + o11*qs.y + o12*qt.y; \
    GO1##c += o10*qr.z + o11*qs.z + o12*qt.z; \
    GO1##d += o10*qr.w + o11*qs.w + o12*qt.w; \
    if (seam) { \
      SE0 += eA0*sm + eA1*sr; \
      SO0 += o00*sm + o01*sr + o02*ss; \
      SE1 += pa0*sr + pa1*ss; \
      SO1 += o10*sr + o11*ss + o12*st; \
    } \
  }

  BANDV(0, qAm,qAr,qAs,qAt, sAm,sAr,sAs,sAt, PE0,PO0,PE1,PO1, SPE0,SPO0,SPE1,SPO1)
  BANDV(1, qBm,qBr,qBs,qBt, sBm,sBr,sBs,sBt, PE0,PO0,PE1,PO1, SPE0,SPO0,SPE1,SPO1)
  BANDV(2, qCm,qCr,qCs,qCt, sCm,sCr,sCs,sCt, QE0,QO0,QE1,QO1, SQE0,SQO0,SQE1,SQO1)
  BANDV(3, qDm,qDr,qDs,qDt, sDm,sDr,sDs,sDt, QE0,QO0,QE1,QO1, SQE0,SQO0,SQE1,SQO1)
#undef BANDV

  // horizontal taps per group (v0 = 1, ratio v1 = f01/f00; rcp exact: f00=±0.5)
  const float vp = F[0].y * __builtin_amdgcn_rcpf(F[0].x);
  const float vq = F[2].y * __builtin_amdgcn_rcpf(F[2].x);
  const float h0p = 0.75f + 0.25f*vp, h1p = 0.25f + 0.75f*vp;
  const float g0p = 0.25f, g1p = 0.75f*(1.f + vp), g2p = 0.25f*vp;
  const float h0q = 0.75f + 0.25f*vq, h1q = 0.25f + 0.75f*vq;
  const float g0q = 0.25f, g1q = 0.75f*(1.f + vq), g2q = 0.25f*vq;
  const float h0pa = le ? 0.f : h0p, h1pa = le ? vp : h1p;
  const float g0pa = le ? 0.f : g0p, g1pa = le ? (1.f + 0.75f*vp) : g1p;
  const float g1pd = re ? (0.75f + vp) : g1p, g2pd = re ? 0.f : g2p;
  const float h0qa = le ? 0.f : h0q, h1qa = le ? vq : h1q;
  const float g0qa = le ? 0.f : g0q, g1qa = le ? (1.f + 0.75f*vq) : g1q;
  const float g1qd = re ? (0.75f + vq) : g1q, g2qd = re ? 0.f : g2q;

  float* op = out + ((size_t)bc * OH + 2 * y0) * OW + 2 * x0;

#define HPASS(P0,P1,P2,P3, Q0,Q1,Q2,Q3, SP,SQ, rowp) { \
    float PL = __shfl_up(P3, 1),  QL = __shfl_up(Q3, 1); \
    float PR = __shfl_down(P0, 1), QR = __shfl_down(Q0, 1); \
    if (needL) { PL = SP; QL = SQ; } \
    if (needR) { PR = SP; QR = SQ; } \
    const float z0 = h0pa*PL + h1pa*P0            + h0qa*QL + h1qa*Q0; \
    const float z1 = g0pa*PL + g1pa*P0 + g2p*P1   + g0qa*QL + g1qa*Q0 + g2q*Q1; \
    const float z2 = h0p*P0  + h1p*P1             + h0q*Q0  + h1q*Q1; \
    const float z3 = g0p*P0  + g1p*P1  + g2p*P2   + g0q*Q0  + g1q*Q1  + g2q*Q2; \
    const float z4 = h0p*P1  + h1p*P2             + h0q*Q1  + h1q*Q2; \
    const float z5 = g0p*P1  + g1p*P2  + g2p*P3   + g0q*Q1  + g1q*Q2  + g2q*Q3; \
    const float z6 = h0p*P2  + h1p*P3             + h0q*Q2  + h1q*Q3; \
    const float z7 = g0p*P2  + g1pd*P3 + g2pd*PR  + g0q*Q2  + g1qd*Q3 + g2qd*QR; \
    const f32x4 Z0 = { z0, z1, z2, z3 }; \
    const f32x4 Z1 = { z4, z5, z6, z7 }; \
    __builtin_nontemporal_store(Z0, (f32x4*)(rowp)); \
    __builtin_nontemporal_store(Z1, (f32x4*)((rowp) + 4)); \
  }

  HPASS(PE0a,PE0b,PE0c,PE0d, QE0a,QE0b,QE0c,QE0d, SPE0,SQE0, op)
  HPASS(PO0a,PO0b,PO0c,PO0d, QO0a,QO0b,QO0c,QO0d, SPO0,SQO0, op + OW)
  HPASS(PE1a,PE1b,PE1c,PE1d, QE1a,QE1b,QE1c,QE1d, SPE1,SQE1, op + 2*OW)
  HPASS(PO1a,PO1b,PO1c,PO1d, QO1a,QO1b,QO1c,QO1d, SPO1,SQO1, op + 3*OW)
#undef HPASS
}

} // namespace

extern "C" void kernel_launch(void* const* d_in, const int* in_sizes, int n_in,
                              void* d_out, int out_size, void* d_ws, size_t ws_size,
                              hipStream_t stream) {
  const float* x   = (const float*)d_in[0];
  const float* fll = (const float*)d_in[1];
  const float* flh = (const float*)d_in[2];
  const float* fhl = (const float*)d_in[3];
  const float* fhh = (const float*)d_in[4];
  float* out = (float*)d_out;

  ihaar<<<dim3(NWG), 256, 0, stream>>>(x, fll, flh, fhl, fhh, out);
}

// Round 8
// 64.465 us; speedup vs baseline: 1.3538x; 1.3538x over previous
//
#include <hip/hip_runtime.h>

namespace {

constexpr int Hh = 512, Ww = 512, OH = 1024, OW = 1024;
constexpr int NB_Y = 256;             // y-blocks (2 input rows each)
constexpr int NBC  = 48;              // 16 batches * 3 out channels
constexpr int NWG  = NB_Y * NBC;      // 12288, % 8 == 0

typedef float f32x4 __attribute__((ext_vector_type(4)));

// Haar butterfly: bands {0,1} share horizontal ratio vP, {2,3} share vQ.
// out = H_vP(V_u0(b0)+V_u1(b1)) + H_vQ(V_u2(b2)+V_u3(b3)).
// All 12 dwordx4 loads issued as one cluster (sched_barrier fence) for MLP.
__global__ __launch_bounds__(256) void ihaar(
    const float* __restrict__ x,
    const float* __restrict__ f0,
    const float* __restrict__ f1,
    const float* __restrict__ f2,
    const float* __restrict__ f3,
    float* __restrict__ out)
{
  // XCD-chunked bijective swizzle (NWG % 8 == 0)
  const int bid = blockIdx.x;
  const int wg  = (bid & 7) * (NWG / 8) + (bid >> 3);
  const int bc   = wg / NB_Y;
  const int yblk = wg - bc * NB_Y;
  const int b = bc / 3;
  const int c = bc - 3 * b;

  const int t    = threadIdx.x;
  const int lane = t & 63;
  const int wv   = t >> 6;
  const int half = wv & 1;
  const int ty   = wv >> 1;
  const int y    = 2 * yblk + ty;
  const int x0   = half * 256 + lane * 4;

  const int u0r = (y > 0) ? y - 1 : 0;
  const int u2r = (y < Hh - 1) ? y + 1 : y;
  const bool needL = (lane == 0)  && (half == 1);   // needs col 255
  const bool needR = (lane == 63) && (half == 0);   // needs col 256
  const bool seam  = needL || needR;
  const bool le = (x0 == 0), re = (x0 == Ww - 4);
  const int sc = needL ? (x0 - 1) : (x0 + 4);

  // filter loads first (uniform -> s_load, latency hidden under q-loads)
  const float4 F[4] = { *(const float4*)f0, *(const float4*)f1,
                        *(const float4*)f2, *(const float4*)f3 };

  const size_t HW = (size_t)Hh * Ww;
  const float* Xa = x + (size_t)(b * 12 + c) * HW;   // band g at Xa + g*3*HW
  const float* Xb = Xa + 3 * HW;
  const float* Xc = Xa + 6 * HW;
  const float* Xd = Xa + 9 * HW;
  const size_t r0 = (size_t)u0r * Ww + x0;
  const size_t r1 = (size_t)y   * Ww + x0;
  const size_t r2 = (size_t)u2r * Ww + x0;

  // ---- issue ALL loads as one cluster ----
  const f32x4 qA0 = *(const f32x4*)(Xa + r0);
  const f32x4 qA1 = *(const f32x4*)(Xa + r1);
  const f32x4 qA2 = *(const f32x4*)(Xa + r2);
  const f32x4 qB0 = *(const f32x4*)(Xb + r0);
  const f32x4 qB1 = *(const f32x4*)(Xb + r1);
  const f32x4 qB2 = *(const f32x4*)(Xb + r2);
  const f32x4 qC0 = *(const f32x4*)(Xc + r0);
  const f32x4 qC1 = *(const f32x4*)(Xc + r1);
  const f32x4 qC2 = *(const f32x4*)(Xc + r2);
  const f32x4 qD0 = *(const f32x4*)(Xd + r0);
  const f32x4 qD1 = *(const f32x4*)(Xd + r1);
  const f32x4 qD2 = *(const f32x4*)(Xd + r2);

  float sA0=0.f,sA1=0.f,sA2=0.f, sB0=0.f,sB1=0.f,sB2=0.f;
  float sC0=0.f,sC1=0.f,sC2=0.f, sD0=0.f,sD1=0.f,sD2=0.f;
  if (seam) {
    const size_t t0 = (size_t)u0r * Ww + sc;
    const size_t t1 = (size_t)y   * Ww + sc;
    const size_t t2 = (size_t)u2r * Ww + sc;
    sA0 = Xa[t0]; sA1 = Xa[t1]; sA2 = Xa[t2];
    sB0 = Xb[t0]; sB1 = Xb[t1]; sB2 = Xb[t2];
    sC0 = Xc[t0]; sC1 = Xc[t1]; sC2 = Xc[t2];
    sD0 = Xd[t0]; sD1 = Xd[t1]; sD2 = Xd[t2];
  }

  // Fence: loads above cannot sink below; math below cannot hoist above.
  __builtin_amdgcn_sched_barrier(0);

  // group accumulators: vertical-combined values at 4 cols, even/odd up-row
  float Pe0,Pe1,Pe2,Pe3, Po0,Po1,Po2,Po3;
  float Qe0,Qe1,Qe2,Qe3, Qo0,Qo1,Qo2,Qo3;
  float SPe=0.f,SPo=0.f,SQe=0.f,SQo=0.f;

#define VTAPS(g, pa0,pa1,pb0,pb1,pb2) \
    float pa0, pa1, pb0, pb1, pb2; { \
    const float uu0 = F[g].x, uu1 = F[g].z; \
    if (y > 0) { pa0 = 0.75f*uu0 + 0.25f*uu1; pa1 = 0.25f*uu0 + 0.75f*uu1; } \
    else       { pa0 = 0.f;                   pa1 = uu1; } \
    if (y == 0)           { pb0 = 0.f;       pb1 = uu0 + 0.75f*uu1; pb2 = 0.25f*uu1; } \
    else if (y == Hh - 1) { pb0 = 0.25f*uu0; pb1 = 0.75f*uu0 + uu1; pb2 = 0.f; } \
    else                  { pb0 = 0.25f*uu0; pb1 = 0.75f*(uu0+uu1); pb2 = 0.25f*uu1; } }

  VTAPS(0, aA0,aA1,bA0,bA1,bA2)
  VTAPS(1, aB0,aB1,bB0,bB1,bB2)
  VTAPS(2, aC0,aC1,bC0,bC1,bC2)
  VTAPS(3, aD0,aD1,bD0,bD1,bD2)
#undef VTAPS

  Pe0 = aA0*qA0.x + aA1*qA1.x + aB0*qB0.x + aB1*qB1.x;
  Pe1 = aA0*qA0.y + aA1*qA1.y + aB0*qB0.y + aB1*qB1.y;
  Pe2 = aA0*qA0.z + aA1*qA1.z + aB0*qB0.z + aB1*qB1.z;
  Pe3 = aA0*qA0.w + aA1*qA1.w + aB0*qB0.w + aB1*qB1.w;
  Po0 = bA0*qA0.x + bA1*qA1.x + bA2*qA2.x + bB0*qB0.x + bB1*qB1.x + bB2*qB2.x;
  Po1 = bA0*qA0.y + bA1*qA1.y + bA2*qA2.y + bB0*qB0.y + bB1*qB1.y + bB2*qB2.y;
  Po2 = bA0*qA0.z + bA1*qA1.z + bA2*qA2.z + bB0*qB0.z + bB1*qB1.z + bB2*qB2.z;
  Po3 = bA0*qA0.w + bA1*qA1.w + bA2*qA2.w + bB0*qB0.w + bB1*qB1.w + bB2*qB2.w;
  Qe0 = aC0*qC0.x + aC1*qC1.x + aD0*qD0.x + aD1*qD1.x;
  Qe1 = aC0*qC0.y + aC1*qC1.y + aD0*qD0.y + aD1*qD1.y;
  Qe2 = aC0*qC0.z + aC1*qC1.z + aD0*qD0.z + aD1*qD1.z;
  Qe3 = aC0*qC0.w + aC1*qC1.w + aD0*qD0.w + aD1*qD1.w;
  Qo0 = bC0*qC0.x + bC1*qC1.x + bC2*qC2.x + bD0*qD0.x + bD1*qD1.x + bD2*qD2.x;
  Qo1 = bC0*qC0.y + bC1*qC1.y + bC2*qC2.y + bD0*qD0.y + bD1*qD1.y + bD2*qD2.y;
  Qo2 = bC0*qC0.z + bC1*qC1.z + bC2*qC2.z + bD0*qD0.z + bD1*qD1.z + bD2*qD2.z;
  Qo3 = bC0*qC0.w + bC1*qC1.w + bC2*qC2.w + bD0*qD0.w + bD1*qD1.w + bD2*qD2.w;
  if (seam) {
    SPe = aA0*sA0 + aA1*sA1 + aB0*sB0 + aB1*sB1;
    SPo = bA0*sA0 + bA1*sA1 + bA2*sA2 + bB0*sB0 + bB1*sB1 + bB2*sB2;
    SQe = aC0*sC0 + aC1*sC1 + aD0*sD0 + aD1*sD1;
    SQo = bC0*sC0 + bC1*sC1 + bC2*sC2 + bD0*sD0 + bD1*sD1 + bD2*sD2;
  }

  // neighbor vertical values across lanes (seam lanes patch from scalars)
  float PeL = __shfl_up(Pe3, 1),  PoL = __shfl_up(Po3, 1);
  float QeL = __shfl_up(Qe3, 1),  QoL = __shfl_up(Qo3, 1);
  float PeR = __shfl_down(Pe0, 1), PoR = __shfl_down(Po0, 1);
  float QeR = __shfl_down(Qe0, 1), QoR = __shfl_down(Qo0, 1);
  if (needL) { PeL = SPe; PoL = SPo; QeL = SQe; QoL = SQo; }
  if (needR) { PeR = SPe; PoR = SPo; QeR = SQe; QoR = SQo; }

  // horizontal taps per group (v0 = 1, ratio v1 = f01/f00; rcp exact: f00=±0.5)
  const float vp = F[0].y * __builtin_amdgcn_rcpf(F[0].x);
  const float vq = F[2].y * __builtin_amdgcn_rcpf(F[2].x);
  const float h0p = 0.75f + 0.25f*vp, h1p = 0.25f + 0.75f*vp;
  const float g0p = 0.25f, g1p = 0.75f*(1.f + vp), g2p = 0.25f*vp;
  const float h0q = 0.75f + 0.25f*vq, h1q = 0.25f + 0.75f*vq;
  const float g0q = 0.25f, g1q = 0.75f*(1.f + vq), g2q = 0.25f*vq;
  const float h0pa = le ? 0.f : h0p, h1pa = le ? vp : h1p;
  const float g0pa = le ? 0.f : g0p, g1pa = le ? (1.f + 0.75f*vp) : g1p;
  const float g1pd = re ? (0.75f + vp) : g1p, g2pd = re ? 0.f : g2p;
  const float h0qa = le ? 0.f : h0q, h1qa = le ? vq : h1q;
  const float g0qa = le ? 0.f : g0q, g1qa = le ? (1.f + 0.75f*vq) : g1q;
  const float g1qd = re ? (0.75f + vq) : g1q, g2qd = re ? 0.f : g2q;

  // even-parity output row (2y)
  const float e0 = h0pa*PeL + h1pa*Pe0           + h0qa*QeL + h1qa*Qe0;
  const float e1 = g0pa*PeL + g1pa*Pe0 + g2p*Pe1 + g0qa*QeL + g1qa*Qe0 + g2q*Qe1;
  const float e2 = h0p*Pe0  + h1p*Pe1            + h0q*Qe0  + h1q*Qe1;
  const float e3 = g0p*Pe0  + g1p*Pe1  + g2p*Pe2 + g0q*Qe0  + g1q*Qe1  + g2q*Qe2;
  const float e4 = h0p*Pe1  + h1p*Pe2            + h0q*Qe1  + h1q*Qe2;
  const float e5 = g0p*Pe1  + g1p*Pe2  + g2p*Pe3 + g0q*Qe1  + g1q*Qe2  + g2q*Qe3;
  const float e6 = h0p*Pe2  + h1p*Pe3            + h0q*Qe2  + h1q*Qe3;
  const float e7 = g0p*Pe2  + g1pd*Pe3 + g2pd*PeR+ g0q*Qe2  + g1qd*Qe3 + g2qd*QeR;
  // odd-parity output row (2y+1)
  const float o0 = h0pa*PoL + h1pa*Po0           + h0qa*QoL + h1qa*Qo0;
  const float o1 = g0pa*PoL + g1pa*Po0 + g2p*Po1 + g0qa*QoL + g1qa*Qo0 + g2q*Qo1;
  const float o2 = h0p*Po0  + h1p*Po1            + h0q*Qo0  + h1q*Qo1;
  const float o3 = g0p*Po0  + g1p*Po1  + g2p*Po2 + g0q*Qo0  + g1q*Qo1  + g2q*Qo2;
  const float o4 = h0p*Po1  + h1p*Po2            + h0q*Qo1  + h1q*Qo2;
  const float o5 = g0p*Po1  + g1p*Po2  + g2p*Po3 + g0q*Qo1  + g1q*Qo2  + g2q*Qo3;
  const float o6 = h0p*Po2  + h1p*Po3            + h0q*Qo2  + h1q*Qo3;
  const float o7 = g0p*Po2  + g1pd*Po3 + g2pd*PoR+ g0q*Qo2  + g1qd*Qo3 + g2qd*QoR;

  float* op = out + ((size_t)bc * OH + 2 * y) * OW + 2 * x0;
  const f32x4 E0 = { e0, e1, e2, e3 };
  const f32x4 E1 = { e4, e5, e6, e7 };
  const f32x4 O0 = { o0, o1, o2, o3 };
  const f32x4 O1 = { o4, o5, o6, o7 };
  __builtin_nontemporal_store(E0, (f32x4*)op);
  __builtin_nontemporal_store(E1, (f32x4*)(op + 4));
  __builtin_nontemporal_store(O0, (f32x4*)(op + OW));
  __builtin_nontemporal_store(O1, (f32x4*)(op + OW + 4));
}

} // namespace

extern "C" void kernel_launch(void* const* d_in, const int* in_sizes, int n_in,
                              void* d_out, int out_size, void* d_ws, size_t ws_size,
                              hipStream_t stream) {
  const float* x   = (const float*)d_in[0];
  const float* fll = (const float*)d_in[1];
  const float* flh = (const float*)d_in[2];
  const float* fhl = (const float*)d_in[3];
  const float* fhh = (const float*)d_in[4];
  float* out = (float*)d_out;

  ihaar<<<dim3(NWG), 256, 0, stream>>>(x, fll, flh, fhl, fhh, out);
}